// Round 9
// baseline (58.808 us; speedup 1.0000x reference)
//
#include <hip/hip_runtime.h>

#define BB 16
#define NN 100000
#define KK 8
#define BLOCK 256

#define ROW_U4 4                              // fp8 row: 4 uint4 = 64B (48 data + 16B zero pad)
#define DT_BYTES ((size_t)NN * 64)            // 6.4 MB
#define GRID1 ((NN + 63) / 64)                // 1563 blocks, 64 vertices each
#define GRID2 (NN * 8 / BLOCK)                // 3125 blocks exactly (800000 threads, no tail)
#define SCALE (1.0f / ((float)BB * NN * 3))

typedef float f32x2 __attribute__((ext_vector_type(2)));

// pack 4 f32 -> 4 fp8 e4m3 (one dword) via HW converts
__device__ __forceinline__ unsigned pk_fp8x4(float a, float b, float c, float d) {
    int v = __builtin_amdgcn_cvt_pk_fp8_f32(a, b, 0, false);   // bytes 0,1
    v     = __builtin_amdgcn_cvt_pk_fp8_f32(c, d, v, true);    // bytes 2,3
    return (unsigned)v;
}

// a[0..15] += wv * unpack16_fp8(u)
__device__ __forceinline__ void fma16(float* a, uint4 u, float wv) {
    f32x2 p;
    p = __builtin_amdgcn_cvt_pk_f32_fp8((int)u.x, false); a[0]  += wv * p.x; a[1]  += wv * p.y;
    p = __builtin_amdgcn_cvt_pk_f32_fp8((int)u.x, true ); a[2]  += wv * p.x; a[3]  += wv * p.y;
    p = __builtin_amdgcn_cvt_pk_f32_fp8((int)u.y, false); a[4]  += wv * p.x; a[5]  += wv * p.y;
    p = __builtin_amdgcn_cvt_pk_f32_fp8((int)u.y, true ); a[6]  += wv * p.x; a[7]  += wv * p.y;
    p = __builtin_amdgcn_cvt_pk_f32_fp8((int)u.z, false); a[8]  += wv * p.x; a[9]  += wv * p.y;
    p = __builtin_amdgcn_cvt_pk_f32_fp8((int)u.z, true ); a[10] += wv * p.x; a[11] += wv * p.y;
    p = __builtin_amdgcn_cvt_pk_f32_fp8((int)u.w, false); a[12] += wv * p.x; a[13] += wv * p.y;
    p = __builtin_amdgcn_cvt_pk_f32_fp8((int)u.w, true ); a[14] += wv * p.x; a[15] += wv * p.y;
}

// ---------- Kernel 1: coalesced diff + LDS transpose + fp8 pack (64B rows) ----------
// dT[n][b*3+c] (fp8 e4m3, 48 data + 16 zero-pad bytes) = geom[b][n][c] - gtp[b][n][c]
__global__ __launch_bounds__(BLOCK) void diff_transpose_fp8_kernel(
    const float4* __restrict__ geom4,
    const float4* __restrict__ gtp4,
    uint4*        __restrict__ dT4,
    float*        __restrict__ out)
{
    __shared__ float tile[64][49];   // [vertex in block][b*3+c], +1 pad
    int tid = threadIdx.x;
    int b = tid >> 4;                // 0..15
    int q = tid & 15;                // n-quad within block
    int nbase = blockIdx.x * 64;
    int n0 = nbase + q * 4;

    if (blockIdx.x == 0 && tid == 0) out[0] = 0.0f;   // zero accumulator (stream-ordered before k2)

    if (n0 < NN) {
        int fi = (b * (NN * 3) + n0 * 3) >> 2;        // float4 index, coalesced
        float4 g0 = geom4[fi], g1 = geom4[fi + 1], g2 = geom4[fi + 2];
        float4 t0 = gtp4[fi],  t1 = gtp4[fi + 1],  t2 = gtp4[fi + 2];
        float d[12] = {g0.x - t0.x, g0.y - t0.y, g0.z - t0.z, g0.w - t0.w,
                       g1.x - t1.x, g1.y - t1.y, g1.z - t1.z, g1.w - t1.w,
                       g2.x - t2.x, g2.y - t2.y, g2.z - t2.z, g2.w - t2.w};
        #pragma unroll
        for (int e = 0; e < 12; ++e)
            tile[q * 4 + e / 3][b * 3 + e % 3] = d[e];
    }
    __syncthreads();

    // 64 rows x 4 uint4 per row = 256 fully-coalesced 16B stores (1 per thread)
    {
        int r = tid >> 2, m = tid & 3;       // m: which uint4 of the 64B row
        int n = nbase + r;
        if (n < NN) {
            uint4 o;
            if (m < 3) {
                const float* row = &tile[r][m * 16];
                o.x = pk_fp8x4(row[0],  row[1],  row[2],  row[3]);
                o.y = pk_fp8x4(row[4],  row[5],  row[6],  row[7]);
                o.z = pk_fp8x4(row[8],  row[9],  row[10], row[11]);
                o.w = pk_fp8x4(row[12], row[13], row[14], row[15]);
            } else {
                o.x = o.y = o.z = o.w = 0u;  // 16B zero pad
            }
            dT4[n * ROW_U4 + m] = o;
        }
    }
}

// ---------- Kernel 2: 8 threads/vertex, two 4-lane quads split the K-neighbors ----------
// t -> n = t>>3, h = (t>>2)&1 (neighbor half), s = t&3 (uint4 within 64B row).
// Each quad consumes exactly one full aligned 64B line per gather.
__global__ __launch_bounds__(BLOCK) void lap_gather_kernel(
    const uint4* __restrict__ dv,
    const int*   __restrict__ idx,
    const float* __restrict__ w,
    float*       __restrict__ out)
{
    int t = blockIdx.x * BLOCK + threadIdx.x;  // 800000 threads, no tail
    int n = t >> 3;
    int h = (t >> 2) & 1;
    int s = t & 3;

    float a[16];
    #pragma unroll
    for (int i = 0; i < 16; ++i) a[i] = 0.0f;

    // this thread's half of idx/w: lanes of the 8-group read 2 adjacent int4s
    const int4*   ip = reinterpret_cast<const int4*>(idx + (size_t)n * KK);
    const float4* wp = reinterpret_cast<const float4*>(w + (size_t)n * KK);
    int4   iv = ip[h];
    float4 wv = wp[h];
    int   js[4] = {iv.x, iv.y, iv.z, iv.w};
    float wk[4] = {wv.x, wv.y, wv.z, wv.w};

    // 4 independent gathers per thread; quad = one full aligned 64B line
    #pragma unroll
    for (int k = 0; k < 4; ++k)
        fma16(a, dv[js[k] * ROW_U4 + s], wk[k]);

    if (h == 0)
        fma16(a, dv[n * ROW_U4 + s], 1.0f);    // self term (h=0 quad only)

    float ssq = 0.0f;
    #pragma unroll
    for (int i = 0; i < 16; ++i) ssq += a[i] * a[i];

    #pragma unroll
    for (int off = 32; off > 0; off >>= 1)
        ssq += __shfl_down(ssq, off, 64);

    __shared__ float wsum[BLOCK / 64];
    int lane = threadIdx.x & 63;
    int wid  = threadIdx.x >> 6;
    if (lane == 0) wsum[wid] = ssq;
    __syncthreads();

    if (threadIdx.x == 0) {
        // plain device-scope atomic: no cache-maintenance pathology (R4-R6 lesson:
        // __threadfence was the killer, not atomics).
        atomicAdd(out, (wsum[0] + wsum[1] + wsum[2] + wsum[3]) * SCALE);
    }
}

extern "C" void kernel_launch(void* const* d_in, const int* in_sizes, int n_in,
                              void* d_out, int out_size, void* d_ws, size_t ws_size,
                              hipStream_t stream) {
    const float* geom = (const float*)d_in[0];
    const float* gtp  = (const float*)d_in[1];
    const int*   idx  = (const int*)d_in[2];
    const float* w    = (const float*)d_in[3];
    float* out = (float*)d_out;

    uint4* dT4 = (uint4*)d_ws;

    diff_transpose_fp8_kernel<<<GRID1, BLOCK, 0, stream>>>(
        (const float4*)geom, (const float4*)gtp, dT4, out);
    lap_gather_kernel<<<GRID2, BLOCK, 0, stream>>>(dT4, idx, w, out);
}

// Round 10
// 28.522 us; speedup vs baseline: 2.0619x; 2.0619x over previous
//
#include <hip/hip_runtime.h>

#define BB 16
#define NN 100000
#define KK 8
#define BLOCK 256

#define ROW_U4 4                              // fp8 row: 4 uint4 = 64B (48 data + 16B zero pad)
#define DT_BYTES ((size_t)NN * 64)            // 6.4 MB
#define GRID1 ((NN + 63) / 64)                // 1563 blocks, 64 vertices each
#define GRID2 (NN * 8 / BLOCK)                // 3125 blocks exactly (800000 threads, no tail)
#define SCALE (1.0f / ((float)BB * NN * 3))

typedef float f32x2 __attribute__((ext_vector_type(2)));

// pack 4 f32 -> 4 fp8 e4m3 (one dword) via HW converts
__device__ __forceinline__ unsigned pk_fp8x4(float a, float b, float c, float d) {
    int v = __builtin_amdgcn_cvt_pk_fp8_f32(a, b, 0, false);   // bytes 0,1
    v     = __builtin_amdgcn_cvt_pk_fp8_f32(c, d, v, true);    // bytes 2,3
    return (unsigned)v;
}

// a[0..15] += wv * unpack16_fp8(u)
__device__ __forceinline__ void fma16(float* a, uint4 u, float wv) {
    f32x2 p;
    p = __builtin_amdgcn_cvt_pk_f32_fp8((int)u.x, false); a[0]  += wv * p.x; a[1]  += wv * p.y;
    p = __builtin_amdgcn_cvt_pk_f32_fp8((int)u.x, true ); a[2]  += wv * p.x; a[3]  += wv * p.y;
    p = __builtin_amdgcn_cvt_pk_f32_fp8((int)u.y, false); a[4]  += wv * p.x; a[5]  += wv * p.y;
    p = __builtin_amdgcn_cvt_pk_f32_fp8((int)u.y, true ); a[6]  += wv * p.x; a[7]  += wv * p.y;
    p = __builtin_amdgcn_cvt_pk_f32_fp8((int)u.z, false); a[8]  += wv * p.x; a[9]  += wv * p.y;
    p = __builtin_amdgcn_cvt_pk_f32_fp8((int)u.z, true ); a[10] += wv * p.x; a[11] += wv * p.y;
    p = __builtin_amdgcn_cvt_pk_f32_fp8((int)u.w, false); a[12] += wv * p.x; a[13] += wv * p.y;
    p = __builtin_amdgcn_cvt_pk_f32_fp8((int)u.w, true ); a[14] += wv * p.x; a[15] += wv * p.y;
}

// ---------- Kernel 1: coalesced diff + LDS transpose + fp8 pack (64B rows) ----------
// dT[n][b*3+c] (fp8 e4m3, 48 data + 16 zero-pad bytes) = geom[b][n][c] - gtp[b][n][c]
__global__ __launch_bounds__(BLOCK) void diff_transpose_fp8_kernel(
    const float4* __restrict__ geom4,
    const float4* __restrict__ gtp4,
    uint4*        __restrict__ dT4)
{
    __shared__ float tile[64][49];   // [vertex in block][b*3+c], +1 pad
    int tid = threadIdx.x;
    int b = tid >> 4;                // 0..15
    int q = tid & 15;                // n-quad within block
    int nbase = blockIdx.x * 64;
    int n0 = nbase + q * 4;

    if (n0 < NN) {
        int fi = (b * (NN * 3) + n0 * 3) >> 2;        // float4 index, coalesced
        float4 g0 = geom4[fi], g1 = geom4[fi + 1], g2 = geom4[fi + 2];
        float4 t0 = gtp4[fi],  t1 = gtp4[fi + 1],  t2 = gtp4[fi + 2];
        float d[12] = {g0.x - t0.x, g0.y - t0.y, g0.z - t0.z, g0.w - t0.w,
                       g1.x - t1.x, g1.y - t1.y, g1.z - t1.z, g1.w - t1.w,
                       g2.x - t2.x, g2.y - t2.y, g2.z - t2.z, g2.w - t2.w};
        #pragma unroll
        for (int e = 0; e < 12; ++e)
            tile[q * 4 + e / 3][b * 3 + e % 3] = d[e];
    }
    __syncthreads();

    // 64 rows x 4 uint4 per row = 256 fully-coalesced 16B stores (1 per thread)
    {
        int r = tid >> 2, m = tid & 3;       // m: which uint4 of the 64B row
        int n = nbase + r;
        if (n < NN) {
            uint4 o;
            if (m < 3) {
                const float* row = &tile[r][m * 16];
                o.x = pk_fp8x4(row[0],  row[1],  row[2],  row[3]);
                o.y = pk_fp8x4(row[4],  row[5],  row[6],  row[7]);
                o.z = pk_fp8x4(row[8],  row[9],  row[10], row[11]);
                o.w = pk_fp8x4(row[12], row[13], row[14], row[15]);
            } else {
                o.x = o.y = o.z = o.w = 0u;  // 16B zero pad
            }
            dT4[n * ROW_U4 + m] = o;
        }
    }
}

// ---------- Kernel 2: 8 threads/vertex, two quads split K; plain partial store ----------
// t -> n = t>>3, h = (t>>2)&1 (neighbor half), s = t&3 (uint4 within 64B row).
// Each quad consumes exactly one full aligned 64B line per gather.
// NO atomics, NO fences: single-address atomicAdd chains cost ~15ns/block
// serialized at the coherence point (R8/R9: k2 time == 15ns x blocks).
__global__ __launch_bounds__(BLOCK) void lap_gather_kernel(
    const uint4* __restrict__ dv,
    const int*   __restrict__ idx,
    const float* __restrict__ w,
    float*       __restrict__ partial)
{
    int t = blockIdx.x * BLOCK + threadIdx.x;  // 800000 threads, no tail
    int n = t >> 3;
    int h = (t >> 2) & 1;
    int s = t & 3;

    float a[16];
    #pragma unroll
    for (int i = 0; i < 16; ++i) a[i] = 0.0f;

    // this thread's half of idx/w: lanes of the 8-group read 2 adjacent int4s
    const int4*   ip = reinterpret_cast<const int4*>(idx + (size_t)n * KK);
    const float4* wp = reinterpret_cast<const float4*>(w + (size_t)n * KK);
    int4   iv = ip[h];
    float4 wv = wp[h];
    int   js[4] = {iv.x, iv.y, iv.z, iv.w};
    float wk[4] = {wv.x, wv.y, wv.z, wv.w};

    // 4 independent gathers per thread; quad = one full aligned 64B line
    #pragma unroll
    for (int k = 0; k < 4; ++k)
        fma16(a, dv[js[k] * ROW_U4 + s], wk[k]);

    if (h == 0)
        fma16(a, dv[n * ROW_U4 + s], 1.0f);    // self term (h=0 quad only)

    float ssq = 0.0f;
    #pragma unroll
    for (int i = 0; i < 16; ++i) ssq += a[i] * a[i];

    #pragma unroll
    for (int off = 32; off > 0; off >>= 1)
        ssq += __shfl_down(ssq, off, 64);

    __shared__ float wsum[BLOCK / 64];
    int lane = threadIdx.x & 63;
    int wid  = threadIdx.x >> 6;
    if (lane == 0) wsum[wid] = ssq;
    __syncthreads();

    if (threadIdx.x == 0)
        partial[blockIdx.x] = wsum[0] + wsum[1] + wsum[2] + wsum[3];
}

// ---------- Kernel 3: tiny final reduce, overwrites out (no zeroing needed) ----------
__global__ __launch_bounds__(BLOCK) void final_reduce_kernel(
    const float* __restrict__ partial,
    float*       __restrict__ out)
{
    float s = 0.0f;
    for (int i = threadIdx.x; i < GRID2; i += BLOCK)
        s += partial[i];

    #pragma unroll
    for (int off = 32; off > 0; off >>= 1)
        s += __shfl_down(s, off, 64);

    __shared__ float wsum[BLOCK / 64];
    int lane = threadIdx.x & 63;
    int wid  = threadIdx.x >> 6;
    if (lane == 0) wsum[wid] = s;
    __syncthreads();

    if (threadIdx.x == 0)
        out[0] = (wsum[0] + wsum[1] + wsum[2] + wsum[3]) * SCALE;
}

extern "C" void kernel_launch(void* const* d_in, const int* in_sizes, int n_in,
                              void* d_out, int out_size, void* d_ws, size_t ws_size,
                              hipStream_t stream) {
    const float* geom = (const float*)d_in[0];
    const float* gtp  = (const float*)d_in[1];
    const int*   idx  = (const int*)d_in[2];
    const float* w    = (const float*)d_in[3];
    float* out = (float*)d_out;

    uint4* dT4     = (uint4*)d_ws;
    float* partial = (float*)((char*)d_ws + DT_BYTES);

    diff_transpose_fp8_kernel<<<GRID1, BLOCK, 0, stream>>>(
        (const float4*)geom, (const float4*)gtp, dT4);
    lap_gather_kernel<<<GRID2, BLOCK, 0, stream>>>(dT4, idx, w, partial);
    final_reduce_kernel<<<1, BLOCK, 0, stream>>>(partial, out);
}